// Round 12
// baseline (314.493 us; speedup 1.0000x reference)
//
#include <hip/hip_runtime.h>
#include <math.h>

#define NUM_CLASSES 26
#define HH 512
#define WW 512
#define NB 4
#define PHH 171
#define PWW 171
#define NHH 169
#define NWW 169
#define MPTS (NHH*NWW)        // 28561
#define NCT (NB*NUM_CLASSES)  // 104
#define CLIPV 1e-6f
#define NCHUNK 25
#define RPC 7                 // 24*7=168 + 1 ragged = 169
#define TROWS 9               // pooled rows per tile (RPC + 2 halo)
#define TW 180                // tile row stride (171 used + pad)
#define NQ 43                 // col quads per row
#define NSLOT 189             // 45 covL + 45 covP + 81 covLP + 9 sumL + 9 sumP

// ---------- Kernel 1: fused maxpool + covariance partials ----------
// grid (nc, chunk). RPC=7: 2600 blocks (10.2/CU), LDS 13 KB -> latency hiding
// via residency (r11: 1352 blocks -> 33% occ, latency-bound at 1.9 TB/s).
__global__ __launch_bounds__(256, 4) void fused_kernel(const float* __restrict__ cls,
        const float* __restrict__ tgt, const float* __restrict__ mask,
        float* __restrict__ partial) {
    const int nc = blockIdx.x, ch = blockIdx.y;
    const int n = nc / NUM_CLASSES;
    const int lane = threadIdx.x & 63, wave = threadIdx.x >> 6;
    const int rowbase = ch * RPC;
    const int rc = (rowbase + RPC <= NHH) ? RPC : (NHH - rowbase);   // 7 or 1
    const int trows = rc + 2;

    __shared__ float tP[TROWS][TW];
    __shared__ float tL[TROWS][TW];

    const float4* c4 = (const float4*)(cls  + (size_t)nc * HH * WW);
    const float4* t4 = (const float4*)(tgt  + (size_t)nc * HH * WW);
    const float4* m4 = (const float4*)(mask + (size_t)n  * HH * WW);

    const int mdiv = lane / 3;
    const int r3   = lane - 3 * mdiv;    // lane % 3

    // ---- Phase 1 ----
    for (int tr = wave; tr < trows; tr += 4) {
        const int ph = rowbase + tr;     // <= 170
        float am[8], lm[8];
        #pragma unroll
        for (int j = 0; j < 8; ++j) { am[j] = -INFINITY; lm[j] = 0.f; }
        const int r0 = 3 * ph - 1;
        #pragma unroll
        for (int s = 0; s < 3; ++s) {
            int r = r0 + s;
            r = r < 0 ? 0 : r;           // ph==0: duplicate row 0 (max-idempotent)
            const float4* rc4 = c4 + r * 128;
            const float4* rt4 = t4 + r * 128;
            const float4* rm4 = m4 + r * 128;
            float4 c0 = rc4[2 * lane], c1 = rc4[2 * lane + 1];
            float4 t0 = rt4[2 * lane], t1 = rt4[2 * lane + 1];
            float4 m0 = rm4[2 * lane], m1 = rm4[2 * lane + 1];
            float cc[8] = {c0.x, c0.y, c0.z, c0.w, c1.x, c1.y, c1.z, c1.w};
            float tt[8] = {t0.x, t0.y, t0.z, t0.w, t1.x, t1.y, t1.z, t1.w};
            float mm[8] = {m0.x, m0.y, m0.z, m0.w, m1.x, m1.y, m1.z, m1.w};
            #pragma unroll
            for (int j = 0; j < 8; ++j) {
                am[j] = fmaxf(am[j], mm[j] > 0.5f ? cc[j] : -INFINITY);
                lm[j] = fmaxf(lm[j], tt[j] * mm[j]);
            }
        }
        // borrow cols 8L+8, 8L+9 from lane+1
        float am8 = __shfl_down(am[0], 1), am9 = __shfl_down(am[1], 1);
        float lm8 = __shfl_down(lm[0], 1), lm9 = __shfl_down(lm[1], 1);

        #define EMIT(p, A, B, Cc, LA, LB, LC) { \
            float a_ = fmaxf(fmaxf(A, B), Cc); \
            float l_ = fmaxf(fmaxf(LA, LB), LC); \
            tP[tr][p] = __fdividef(1.0f, 1.0f + __expf(-a_)) + CLIPV; \
            tL[tr][p] = (l_ > 0.5f) ? 1.0f : 0.0f; }
        if (r3 == 0) {
            int p = 8 * mdiv + 1;
            EMIT(p,     am[2], am[3], am[4], lm[2], lm[3], lm[4]);
            EMIT(p + 1, am[5], am[6], am[7], lm[5], lm[6], lm[7]);
            if (lane == 0) {   // p=0: window cols -1,0,1 -> clamp
                float a_ = fmaxf(am[0], am[1]);
                float l_ = fmaxf(lm[0], lm[1]);
                tP[tr][0] = __fdividef(1.0f, 1.0f + __expf(-a_)) + CLIPV;
                tL[tr][0] = (l_ > 0.5f) ? 1.0f : 0.0f;
            }
        } else if (r3 == 1) {
            int p = 8 * mdiv + 3;
            EMIT(p,     am[0], am[1], am[2], lm[0], lm[1], lm[2]);
            EMIT(p + 1, am[3], am[4], am[5], lm[3], lm[4], lm[5]);
            EMIT(p + 2, am[6], am[7], am8,  lm[6], lm[7], lm8);
        } else {
            int p = 8 * mdiv + 6;
            EMIT(p,     am[1], am[2], am[3], lm[1], lm[2], lm[3]);
            EMIT(p + 1, am[4], am[5], am[6], lm[4], lm[5], lm[6]);
            EMIT(p + 2, am[7], am8,  am9,   lm[7], lm8,  lm9);
        }
        #undef EMIT
        if (lane < 9) {                  // zero pad cols 171..179
            tP[tr][171 + lane] = 0.f;
            tL[tr][171 + lane] = 0.f;
        }
    }
    __syncthreads();

    // ---- Phase 2: wave = mode ----
    const int items = rc * NQ;
    float* pbase = partial + (size_t)ch * NSLOT * NCT + nc;

    if (wave < 2) {
        const float (*src)[TW] = wave ? tP : tL;
        float acc[45], sm[9];
        #pragma unroll
        for (int k = 0; k < 45; ++k) acc[k] = 0.f;
        #pragma unroll
        for (int k = 0; k < 9; ++k) sm[k] = 0.f;

        for (int it = lane; it < items; it += 64) {
            int tr = it / NQ;
            int j0 = (it - tr * NQ) * 4;
            const float* rp = &src[tr][j0];
            float4 x0 = *(const float4*)(rp);
            float4 x1 = *(const float4*)(rp + 4);
            float4 y0 = *(const float4*)(rp + TW);
            float4 y1 = *(const float4*)(rp + TW + 4);
            float4 z0 = *(const float4*)(rp + 2 * TW);
            float4 z1 = *(const float4*)(rp + 2 * TW + 4);
            float r0[8] = {x0.x, x0.y, x0.z, x0.w, x1.x, x1.y, x1.z, x1.w};
            float r1[8] = {y0.x, y0.y, y0.z, y0.w, y1.x, y1.y, y1.z, y1.w};
            float r2[8] = {z0.x, z0.y, z0.z, z0.w, z1.x, z1.y, z1.z, z1.w};
            #pragma unroll
            for (int q = 0; q < 4; ++q) {
                float sel = (j0 + q < NWW) ? 1.f : 0.f;
                float v[9], vs[9];
                v[0] = r0[q]; v[1] = r0[q + 1]; v[2] = r0[q + 2];
                v[3] = r1[q]; v[4] = r1[q + 1]; v[5] = r1[q + 2];
                v[6] = r2[q]; v[7] = r2[q + 1]; v[8] = r2[q + 2];
                #pragma unroll
                for (int d = 0; d < 9; ++d) { vs[d] = v[d] * sel; sm[d] += vs[d]; }
                int k = 0;
                #pragma unroll
                for (int d = 0; d < 9; ++d)
                    #pragma unroll
                    for (int e = d; e < 9; ++e)
                        acc[k++] += vs[d] * v[e];
            }
        }
        #pragma unroll
        for (int k = 0; k < 45; ++k) {
            float x = acc[k];
            #pragma unroll
            for (int off = 32; off > 0; off >>= 1) x += __shfl_down(x, off);
            if (lane == 0) pbase[(size_t)((wave == 0 ? 0 : 45) + k) * NCT] = x;
        }
        #pragma unroll
        for (int k = 0; k < 9; ++k) {
            float x = sm[k];
            #pragma unroll
            for (int off = 32; off > 0; off >>= 1) x += __shfl_down(x, off);
            if (lane == 0) pbase[(size_t)((wave == 0 ? 171 : 180) + k) * NCT] = x;
        }
    } else {
        // LPa (wave 2): d=0..4 ; LPb (wave 3): d=5..8
        const int nd  = (wave == 2) ? 5 : 4;
        const int dof = (wave == 2) ? 0 : 5;
        float acc[45];
        #pragma unroll
        for (int k = 0; k < 45; ++k) acc[k] = 0.f;

        for (int it = lane; it < items; it += 64) {
            int tr = it / NQ;
            int j0 = (it - tr * NQ) * 4;
            const float* pp = &tP[tr][j0];
            float4 px0 = *(const float4*)(pp);
            float4 px1 = *(const float4*)(pp + 4);
            float4 py0 = *(const float4*)(pp + TW);
            float4 py1 = *(const float4*)(pp + TW + 4);
            float4 pz0 = *(const float4*)(pp + 2 * TW);
            float4 pz1 = *(const float4*)(pp + 2 * TW + 4);
            float pr0[8] = {px0.x, px0.y, px0.z, px0.w, px1.x, px1.y, px1.z, px1.w};
            float pr1[8] = {py0.x, py0.y, py0.z, py0.w, py1.x, py1.y, py1.z, py1.w};
            float pr2[8] = {pz0.x, pz0.y, pz0.z, pz0.w, pz1.x, pz1.y, pz1.z, pz1.w};
            const float* la  = &tL[tr + (wave == 2 ? 0 : 1)][j0];
            const float* lb2 = &tL[tr + (wave == 2 ? 1 : 2)][j0];
            float4 la0 = *(const float4*)(la);
            float4 la1 = *(const float4*)(la + 4);
            float4 lb0 = *(const float4*)(lb2);
            float4 lb1 = *(const float4*)(lb2 + 4);
            float lrA[8] = {la0.x, la0.y, la0.z, la0.w, la1.x, la1.y, la1.z, la1.w};
            float lrB[8] = {lb0.x, lb0.y, lb0.z, lb0.w, lb1.x, lb1.y, lb1.z, lb1.w};
            #pragma unroll
            for (int q = 0; q < 4; ++q) {
                float sel = (j0 + q < NWW) ? 1.f : 0.f;
                float vp[9];
                vp[0] = pr0[q]; vp[1] = pr0[q + 1]; vp[2] = pr0[q + 2];
                vp[3] = pr1[q]; vp[4] = pr1[q + 1]; vp[5] = pr1[q + 2];
                vp[6] = pr2[q]; vp[7] = pr2[q + 1]; vp[8] = pr2[q + 2];
                float vl[5];
                if (wave == 2) {
                    vl[0] = lrA[q] * sel; vl[1] = lrA[q + 1] * sel; vl[2] = lrA[q + 2] * sel;
                    vl[3] = lrB[q] * sel; vl[4] = lrB[q + 1] * sel;
                } else {
                    vl[0] = lrA[q + 2] * sel;
                    vl[1] = lrB[q] * sel; vl[2] = lrB[q + 1] * sel; vl[3] = lrB[q + 2] * sel;
                }
                #pragma unroll
                for (int d = 0; d < 5; ++d) {
                    if (d < nd) {
                        #pragma unroll
                        for (int e = 0; e < 9; ++e)
                            acc[d * 9 + e] += vl[d] * vp[e];
                    }
                }
            }
        }
        const int nred = nd * 9;
        #pragma unroll
        for (int k = 0; k < 45; ++k) {
            if (k < nred) {
                float x = acc[k];
                #pragma unroll
                for (int off = 32; off > 0; off >>= 1) x += __shfl_down(x, off);
                if (lane == 0) pbase[(size_t)(90 + dof * 9 + k) * NCT] = x;
            }
        }
    }
}

// ---------- Kernel 2: cooperative per-(n,c) 9x9 algebra ----------
__global__ __launch_bounds__(128) void solve_kernel(const float* __restrict__ partial,
                                                    double* __restrict__ per_nc) {
    const int nc = blockIdx.x;
    const int tid = threadIdx.x;
    __shared__ double cl[45], cp[45], clp[81], sL[9], sP[9];
    __shared__ double All[81], C[81], Pm[81], X[81], A[81];
    __shared__ double logacc;

    for (int s = tid; s < NSLOT; s += 128) {
        double acc = 0.0;
        for (int sl = 0; sl < NCHUNK; ++sl)
            acc += (double)partial[((size_t)sl * NSLOT + s) * NCT + nc];
        if (s < 45)       cl[s] = acc;
        else if (s < 90)  cp[s - 45] = acc;
        else if (s < 171) clp[s - 90] = acc;
        else if (s < 180) sL[s - 171] = acc;
        else              sP[s - 180] = acc;
    }
    if (tid == 0) logacc = 0.0;
    __syncthreads();

    const double M = (double)MPTS;
    if (tid < 81) {
        int d = tid / 9, e = tid % 9;
        int lo = d < e ? d : e, hi = d < e ? e : d;
        int k = 9 * lo - lo * (lo - 1) / 2 + (hi - lo);
        All[tid] = cl[k] - sL[d] * sL[e] / M;
        C[tid]   = cp[k] - sP[d] * sP[e] / M + (d == e ? 1e-3 : 0.0);
        Pm[tid]  = clp[tid] - sL[d] * sP[e] / M;
    }
    __syncthreads();

    for (int k = 0; k < 9; ++k) {
        if (tid == 0) C[k * 9 + k] = sqrt(fmax(C[k * 9 + k], 1e-30));
        __syncthreads();
        if (tid > k && tid < 9) C[tid * 9 + k] /= C[k * 9 + k];
        __syncthreads();
        if (tid < 81) {
            int i = tid / 9, j = tid % 9;
            if (j > k && i >= j) C[i * 9 + j] -= C[i * 9 + k] * C[j * 9 + k];
        }
        __syncthreads();
    }

    for (int e = 0; e < 9; ++e) {
        if (tid < 9) {
            int d = tid;
            double sum = Pm[d * 9 + e];
            for (int k = 0; k < e; ++k) sum -= C[e * 9 + k] * X[k * 9 + d];
            X[e * 9 + d] = sum / C[e * 9 + e];
        }
        __syncthreads();
    }

    if (tid < 81) {
        int d = tid / 9, g = tid % 9;
        double w = 0.0;
        #pragma unroll
        for (int e = 0; e < 9; ++e) w += X[e * 9 + d] * X[e * 9 + g];
        A[tid] = All[tid] - w + (d == g ? 1e-3 : 0.0);
    }
    __syncthreads();

    for (int k = 0; k < 9; ++k) {
        if (tid == 0) {
            double piv = sqrt(fmax(A[k * 9 + k], 0.0));
            A[k * 9 + k] = piv;
            logacc += log(piv + 1e-8);
        }
        __syncthreads();
        if (tid > k && tid < 9) A[tid * 9 + k] /= A[k * 9 + k];
        __syncthreads();
        if (tid < 81) {
            int i = tid / 9, j = tid % 9;
            if (j > k && i >= j) A[i * 9 + j] -= A[i * 9 + k] * A[j * 9 + k];
        }
        __syncthreads();
    }
    if (tid == 0) per_nc[nc] = logacc;
}

// ---------- Kernel 3: final reduction ----------
__global__ __launch_bounds__(128) void reduce_kernel(const double* __restrict__ per_nc,
                                                     float* __restrict__ out) {
    int t = threadIdx.x;
    double r = (t < NCT) ? per_nc[t] : 0.0;
    __shared__ double red[128];
    red[t] = r;
    __syncthreads();
    for (int s = 64; s > 0; s >>= 1) {
        if (t < s) red[t] += red[t + s];
        __syncthreads();
    }
    if (t == 0) out[0] = (float)(red[0] / 36.0);
}

extern "C" void kernel_launch(void* const* d_in, const int* in_sizes, int n_in,
                              void* d_out, int out_size, void* d_ws, size_t ws_size,
                              hipStream_t stream) {
    const float* cls  = (const float*)d_in[0];
    const float* tgt  = (const float*)d_in[1];
    const float* mask = (const float*)d_in[2];

    double* per_nc  = (double*)d_ws;                     // 128 doubles
    float*  partial = (float*)(per_nc + 128);            // NCHUNK*NSLOT*NCT floats

    dim3 gfused(NCT, NCHUNK);
    fused_kernel<<<gfused, 256, 0, stream>>>(cls, tgt, mask, partial);

    solve_kernel<<<NCT, 128, 0, stream>>>(partial, per_nc);

    reduce_kernel<<<1, 128, 0, stream>>>(per_nc, (float*)d_out);
}

// Round 13
// 279.946 us; speedup vs baseline: 1.1234x; 1.1234x over previous
//
#include <hip/hip_runtime.h>
#include <math.h>

#define NUM_CLASSES 26
#define HH 512
#define WW 512
#define NB 4
#define PHH 171
#define PWW 171
#define NHH 169
#define NWW 169
#define MPTS (NHH*NWW)        // 28561
#define NCT (NB*NUM_CLASSES)  // 104
#define CLIPV 1e-6f
#define NCHUNK 16
#define RPC 11                // 15*11=165 + last chunk 4 = 169
#define TROWS 13              // pooled rows per tile (RPC + 2 halo)
#define TW 180                // tile row stride (171 used + pad)
#define NQ 43                 // col quads per row
#define NSLOT 189             // 45 covL + 45 covP + 81 covLP + 9 sumL + 9 sumP

// ---------- Kernel 1: fused maxpool + covariance partials ----------
// grid (nc, chunk) = 1664 blocks (6.5/CU). LDS 18.7 KB (8 blocks/CU by LDS).
// NO waves-per-EU constraint: let the allocator use ~96-128 VGPR to stage
// phase-1's 18 independent loads deep (r9-r12 showed a forced VGPR cap
// starves memory-level parallelism; rate ∝ resident waves × staged loads).
__global__ __launch_bounds__(256) void fused_kernel(const float* __restrict__ cls,
        const float* __restrict__ tgt, const float* __restrict__ mask,
        float* __restrict__ partial) {
    const int nc = blockIdx.x, ch = blockIdx.y;
    const int n = nc / NUM_CLASSES;
    const int lane = threadIdx.x & 63, wave = threadIdx.x >> 6;
    const int rowbase = ch * RPC;
    const int rc = (rowbase + RPC <= NHH) ? RPC : (NHH - rowbase);   // 11 or 4
    const int trows = rc + 2;

    __shared__ float tP[TROWS][TW];
    __shared__ float tL[TROWS][TW];

    const float4* c4 = (const float4*)(cls  + (size_t)nc * HH * WW);
    const float4* t4 = (const float4*)(tgt  + (size_t)nc * HH * WW);
    const float4* m4 = (const float4*)(mask + (size_t)n  * HH * WW);

    const int mdiv = lane / 3;
    const int r3   = lane - 3 * mdiv;    // lane % 3

    // ---- Phase 1: per-wave pooled rows, register vertical max + shuffle halo ----
    for (int tr = wave; tr < trows; tr += 4) {
        const int ph = rowbase + tr;     // <= 170
        float am[8], lm[8];
        #pragma unroll
        for (int j = 0; j < 8; ++j) { am[j] = -INFINITY; lm[j] = 0.f; }
        const int r0 = 3 * ph - 1;
        #pragma unroll
        for (int s = 0; s < 3; ++s) {
            int r = r0 + s;
            r = r < 0 ? 0 : r;           // ph==0: duplicate row 0 (max-idempotent)
            const float4* rc4 = c4 + r * 128;
            const float4* rt4 = t4 + r * 128;
            const float4* rm4 = m4 + r * 128;
            float4 c0 = rc4[2 * lane], c1 = rc4[2 * lane + 1];
            float4 t0 = rt4[2 * lane], t1 = rt4[2 * lane + 1];
            float4 m0 = rm4[2 * lane], m1 = rm4[2 * lane + 1];
            float cc[8] = {c0.x, c0.y, c0.z, c0.w, c1.x, c1.y, c1.z, c1.w};
            float tt[8] = {t0.x, t0.y, t0.z, t0.w, t1.x, t1.y, t1.z, t1.w};
            float mm[8] = {m0.x, m0.y, m0.z, m0.w, m1.x, m1.y, m1.z, m1.w};
            #pragma unroll
            for (int j = 0; j < 8; ++j) {
                am[j] = fmaxf(am[j], mm[j] > 0.5f ? cc[j] : -INFINITY);
                lm[j] = fmaxf(lm[j], tt[j] * mm[j]);
            }
        }
        // borrow cols 8L+8, 8L+9 from lane+1
        float am8 = __shfl_down(am[0], 1), am9 = __shfl_down(am[1], 1);
        float lm8 = __shfl_down(lm[0], 1), lm9 = __shfl_down(lm[1], 1);

        #define EMIT(p, A, B, Cc, LA, LB, LC) { \
            float a_ = fmaxf(fmaxf(A, B), Cc); \
            float l_ = fmaxf(fmaxf(LA, LB), LC); \
            tP[tr][p] = __fdividef(1.0f, 1.0f + __expf(-a_)) + CLIPV; \
            tL[tr][p] = (l_ > 0.5f) ? 1.0f : 0.0f; }
        if (r3 == 0) {
            int p = 8 * mdiv + 1;
            EMIT(p,     am[2], am[3], am[4], lm[2], lm[3], lm[4]);
            EMIT(p + 1, am[5], am[6], am[7], lm[5], lm[6], lm[7]);
            if (lane == 0) {   // p=0: window cols -1,0,1 -> clamp
                float a_ = fmaxf(am[0], am[1]);
                float l_ = fmaxf(lm[0], lm[1]);
                tP[tr][0] = __fdividef(1.0f, 1.0f + __expf(-a_)) + CLIPV;
                tL[tr][0] = (l_ > 0.5f) ? 1.0f : 0.0f;
            }
        } else if (r3 == 1) {
            int p = 8 * mdiv + 3;
            EMIT(p,     am[0], am[1], am[2], lm[0], lm[1], lm[2]);
            EMIT(p + 1, am[3], am[4], am[5], lm[3], lm[4], lm[5]);
            EMIT(p + 2, am[6], am[7], am8,  lm[6], lm[7], lm8);
        } else {
            int p = 8 * mdiv + 6;
            EMIT(p,     am[1], am[2], am[3], lm[1], lm[2], lm[3]);
            EMIT(p + 1, am[4], am[5], am[6], lm[4], lm[5], lm[6]);
            EMIT(p + 2, am[7], am8,  am9,   lm[7], lm8,  lm9);
        }
        #undef EMIT
        if (lane < 9) {                  // zero pad cols 171..179
            tP[tr][171 + lane] = 0.f;
            tL[tr][171 + lane] = 0.f;
        }
    }
    __syncthreads();

    // ---- Phase 2: wave = mode ----
    const int items = rc * NQ;
    float* pbase = partial + (size_t)ch * NSLOT * NCT + nc;

    if (wave < 2) {
        const float (*src)[TW] = wave ? tP : tL;
        float acc[45], sm[9];
        #pragma unroll
        for (int k = 0; k < 45; ++k) acc[k] = 0.f;
        #pragma unroll
        for (int k = 0; k < 9; ++k) sm[k] = 0.f;

        for (int it = lane; it < items; it += 64) {
            int tr = it / NQ;
            int j0 = (it - tr * NQ) * 4;
            const float* rp = &src[tr][j0];
            float4 x0 = *(const float4*)(rp);
            float4 x1 = *(const float4*)(rp + 4);
            float4 y0 = *(const float4*)(rp + TW);
            float4 y1 = *(const float4*)(rp + TW + 4);
            float4 z0 = *(const float4*)(rp + 2 * TW);
            float4 z1 = *(const float4*)(rp + 2 * TW + 4);
            float r0[8] = {x0.x, x0.y, x0.z, x0.w, x1.x, x1.y, x1.z, x1.w};
            float r1[8] = {y0.x, y0.y, y0.z, y0.w, y1.x, y1.y, y1.z, y1.w};
            float r2[8] = {z0.x, z0.y, z0.z, z0.w, z1.x, z1.y, z1.z, z1.w};
            #pragma unroll
            for (int q = 0; q < 4; ++q) {
                float sel = (j0 + q < NWW) ? 1.f : 0.f;
                float v[9], vs[9];
                v[0] = r0[q]; v[1] = r0[q + 1]; v[2] = r0[q + 2];
                v[3] = r1[q]; v[4] = r1[q + 1]; v[5] = r1[q + 2];
                v[6] = r2[q]; v[7] = r2[q + 1]; v[8] = r2[q + 2];
                #pragma unroll
                for (int d = 0; d < 9; ++d) { vs[d] = v[d] * sel; sm[d] += vs[d]; }
                int k = 0;
                #pragma unroll
                for (int d = 0; d < 9; ++d)
                    #pragma unroll
                    for (int e = d; e < 9; ++e)
                        acc[k++] += vs[d] * v[e];
            }
        }
        #pragma unroll
        for (int k = 0; k < 45; ++k) {
            float x = acc[k];
            #pragma unroll
            for (int off = 32; off > 0; off >>= 1) x += __shfl_down(x, off);
            if (lane == 0) pbase[(size_t)((wave == 0 ? 0 : 45) + k) * NCT] = x;
        }
        #pragma unroll
        for (int k = 0; k < 9; ++k) {
            float x = sm[k];
            #pragma unroll
            for (int off = 32; off > 0; off >>= 1) x += __shfl_down(x, off);
            if (lane == 0) pbase[(size_t)((wave == 0 ? 171 : 180) + k) * NCT] = x;
        }
    } else {
        // LPa (wave 2): d=0..4 ; LPb (wave 3): d=5..8
        const int nd  = (wave == 2) ? 5 : 4;
        const int dof = (wave == 2) ? 0 : 5;
        float acc[45];
        #pragma unroll
        for (int k = 0; k < 45; ++k) acc[k] = 0.f;

        for (int it = lane; it < items; it += 64) {
            int tr = it / NQ;
            int j0 = (it - tr * NQ) * 4;
            const float* pp = &tP[tr][j0];
            float4 px0 = *(const float4*)(pp);
            float4 px1 = *(const float4*)(pp + 4);
            float4 py0 = *(const float4*)(pp + TW);
            float4 py1 = *(const float4*)(pp + TW + 4);
            float4 pz0 = *(const float4*)(pp + 2 * TW);
            float4 pz1 = *(const float4*)(pp + 2 * TW + 4);
            float pr0[8] = {px0.x, px0.y, px0.z, px0.w, px1.x, px1.y, px1.z, px1.w};
            float pr1[8] = {py0.x, py0.y, py0.z, py0.w, py1.x, py1.y, py1.z, py1.w};
            float pr2[8] = {pz0.x, pz0.y, pz0.z, pz0.w, pz1.x, pz1.y, pz1.z, pz1.w};
            const float* la  = &tL[tr + (wave == 2 ? 0 : 1)][j0];
            const float* lb2 = &tL[tr + (wave == 2 ? 1 : 2)][j0];
            float4 la0 = *(const float4*)(la);
            float4 la1 = *(const float4*)(la + 4);
            float4 lb0 = *(const float4*)(lb2);
            float4 lb1 = *(const float4*)(lb2 + 4);
            float lrA[8] = {la0.x, la0.y, la0.z, la0.w, la1.x, la1.y, la1.z, la1.w};
            float lrB[8] = {lb0.x, lb0.y, lb0.z, lb0.w, lb1.x, lb1.y, lb1.z, lb1.w};
            #pragma unroll
            for (int q = 0; q < 4; ++q) {
                float sel = (j0 + q < NWW) ? 1.f : 0.f;
                float vp[9];
                vp[0] = pr0[q]; vp[1] = pr0[q + 1]; vp[2] = pr0[q + 2];
                vp[3] = pr1[q]; vp[4] = pr1[q + 1]; vp[5] = pr1[q + 2];
                vp[6] = pr2[q]; vp[7] = pr2[q + 1]; vp[8] = pr2[q + 2];
                float vl[5];
                if (wave == 2) {
                    vl[0] = lrA[q] * sel; vl[1] = lrA[q + 1] * sel; vl[2] = lrA[q + 2] * sel;
                    vl[3] = lrB[q] * sel; vl[4] = lrB[q + 1] * sel;
                } else {
                    vl[0] = lrA[q + 2] * sel;
                    vl[1] = lrB[q] * sel; vl[2] = lrB[q + 1] * sel; vl[3] = lrB[q + 2] * sel;
                }
                #pragma unroll
                for (int d = 0; d < 5; ++d) {
                    if (d < nd) {
                        #pragma unroll
                        for (int e = 0; e < 9; ++e)
                            acc[d * 9 + e] += vl[d] * vp[e];
                    }
                }
            }
        }
        const int nred = nd * 9;
        #pragma unroll
        for (int k = 0; k < 45; ++k) {
            if (k < nred) {
                float x = acc[k];
                #pragma unroll
                for (int off = 32; off > 0; off >>= 1) x += __shfl_down(x, off);
                if (lane == 0) pbase[(size_t)(90 + dof * 9 + k) * NCT] = x;
            }
        }
    }
}

// ---------- Kernel 2: cooperative per-(n,c) 9x9 algebra ----------
__global__ __launch_bounds__(128) void solve_kernel(const float* __restrict__ partial,
                                                    double* __restrict__ per_nc) {
    const int nc = blockIdx.x;
    const int tid = threadIdx.x;
    __shared__ double cl[45], cp[45], clp[81], sL[9], sP[9];
    __shared__ double All[81], C[81], Pm[81], X[81], A[81];
    __shared__ double logacc;

    for (int s = tid; s < NSLOT; s += 128) {
        double acc = 0.0;
        for (int sl = 0; sl < NCHUNK; ++sl)
            acc += (double)partial[((size_t)sl * NSLOT + s) * NCT + nc];
        if (s < 45)       cl[s] = acc;
        else if (s < 90)  cp[s - 45] = acc;
        else if (s < 171) clp[s - 90] = acc;
        else if (s < 180) sL[s - 171] = acc;
        else              sP[s - 180] = acc;
    }
    if (tid == 0) logacc = 0.0;
    __syncthreads();

    const double M = (double)MPTS;
    if (tid < 81) {
        int d = tid / 9, e = tid % 9;
        int lo = d < e ? d : e, hi = d < e ? e : d;
        int k = 9 * lo - lo * (lo - 1) / 2 + (hi - lo);
        All[tid] = cl[k] - sL[d] * sL[e] / M;
        C[tid]   = cp[k] - sP[d] * sP[e] / M + (d == e ? 1e-3 : 0.0);
        Pm[tid]  = clp[tid] - sL[d] * sP[e] / M;
    }
    __syncthreads();

    for (int k = 0; k < 9; ++k) {
        if (tid == 0) C[k * 9 + k] = sqrt(fmax(C[k * 9 + k], 1e-30));
        __syncthreads();
        if (tid > k && tid < 9) C[tid * 9 + k] /= C[k * 9 + k];
        __syncthreads();
        if (tid < 81) {
            int i = tid / 9, j = tid % 9;
            if (j > k && i >= j) C[i * 9 + j] -= C[i * 9 + k] * C[j * 9 + k];
        }
        __syncthreads();
    }

    for (int e = 0; e < 9; ++e) {
        if (tid < 9) {
            int d = tid;
            double sum = Pm[d * 9 + e];
            for (int k = 0; k < e; ++k) sum -= C[e * 9 + k] * X[k * 9 + d];
            X[e * 9 + d] = sum / C[e * 9 + e];
        }
        __syncthreads();
    }

    if (tid < 81) {
        int d = tid / 9, g = tid % 9;
        double w = 0.0;
        #pragma unroll
        for (int e = 0; e < 9; ++e) w += X[e * 9 + d] * X[e * 9 + g];
        A[tid] = All[tid] - w + (d == g ? 1e-3 : 0.0);
    }
    __syncthreads();

    for (int k = 0; k < 9; ++k) {
        if (tid == 0) {
            double piv = sqrt(fmax(A[k * 9 + k], 0.0));
            A[k * 9 + k] = piv;
            logacc += log(piv + 1e-8);
        }
        __syncthreads();
        if (tid > k && tid < 9) A[tid * 9 + k] /= A[k * 9 + k];
        __syncthreads();
        if (tid < 81) {
            int i = tid / 9, j = tid % 9;
            if (j > k && i >= j) A[i * 9 + j] -= A[i * 9 + k] * A[j * 9 + k];
        }
        __syncthreads();
    }
    if (tid == 0) per_nc[nc] = logacc;
}

// ---------- Kernel 3: final reduction ----------
__global__ __launch_bounds__(128) void reduce_kernel(const double* __restrict__ per_nc,
                                                     float* __restrict__ out) {
    int t = threadIdx.x;
    double r = (t < NCT) ? per_nc[t] : 0.0;
    __shared__ double red[128];
    red[t] = r;
    __syncthreads();
    for (int s = 64; s > 0; s >>= 1) {
        if (t < s) red[t] += red[t + s];
        __syncthreads();
    }
    if (t == 0) out[0] = (float)(red[0] / 36.0);
}

extern "C" void kernel_launch(void* const* d_in, const int* in_sizes, int n_in,
                              void* d_out, int out_size, void* d_ws, size_t ws_size,
                              hipStream_t stream) {
    const float* cls  = (const float*)d_in[0];
    const float* tgt  = (const float*)d_in[1];
    const float* mask = (const float*)d_in[2];

    double* per_nc  = (double*)d_ws;                     // 128 doubles
    float*  partial = (float*)(per_nc + 128);            // NCHUNK*NSLOT*NCT floats

    dim3 gfused(NCT, NCHUNK);
    fused_kernel<<<gfused, 256, 0, stream>>>(cls, tgt, mask, partial);

    solve_kernel<<<NCT, 128, 0, stream>>>(partial, per_nc);

    reduce_kernel<<<1, 128, 0, stream>>>(per_nc, (float*)d_out);
}